// Round 13
// baseline (252.640 us; speedup 1.0000x reference)
//
#include <hip/hip_runtime.h>
#include <math.h>

typedef __attribute__((ext_vector_type(8))) short short8;
typedef __attribute__((ext_vector_type(4))) float f32x4;

#define NBSH 9          // 512 nodes per bin
#define MAXBIN 128

__device__ inline unsigned fenc(float f){
  unsigned u = __float_as_uint(f);
  return u ^ ((u >> 31) ? 0xFFFFFFFFu : 0x80000000u);
}
__device__ inline float fdec(unsigned k){
  unsigned u = (k & 0x80000000u) ? (k ^ 0x80000000u) : ~k;
  return __uint_as_float(u);
}
__device__ inline unsigned short bf16rne(float f){
  unsigned u = __float_as_uint(f);
  return (unsigned short)((u + 0x7FFFu + ((u >> 16) & 1u)) >> 16);
}

// ---------------- CSR build ----------------
__global__ __launch_bounds__(256) void k_hist(const int* __restrict__ dst, int* __restrict__ deg, int E){
  int e = blockIdx.x*256 + threadIdx.x;
  if (e < E) atomicAdd(&deg[dst[e]], 1);
}

__global__ __launch_bounds__(256) void k_scan_local(const int* __restrict__ deg, int* __restrict__ offs,
    int* __restrict__ blksum, int nelem, int ndeg){
  __shared__ int sh[256];
  int t = threadIdx.x;
  int i = blockIdx.x*256 + t;
  int v = (i < ndeg) ? deg[i] : 0;
  sh[t] = v; __syncthreads();
  for (int d = 1; d < 256; d <<= 1){
    int add = (t >= d) ? sh[t-d] : 0; __syncthreads();
    sh[t] += add; __syncthreads();
  }
  if (i < nelem) offs[i] = sh[t] - v;   // exclusive
  if (t == 255) blksum[blockIdx.x] = sh[t];
}

__global__ __launch_bounds__(256) void k_scan_blk(int* __restrict__ blksum, int nb){
  __shared__ int sh[256];
  int t = threadIdx.x;
  int running = 0;
  for (int base = 0; base < nb; base += 256){
    int v = (base+t < nb) ? blksum[base+t] : 0;
    __syncthreads();
    sh[t] = v; __syncthreads();
    for (int d = 1; d < 256; d <<= 1){
      int add = (t >= d) ? sh[t-d] : 0; __syncthreads();
      sh[t] += add; __syncthreads();
    }
    if (base+t < nb) blksum[base+t] = running + sh[t] - v;
    running += sh[255];
  }
}

// also seeds bincur[b] = offs[b<<NBSH]  (bin regions are CSR sub-ranges)
__global__ __launch_bounds__(256) void k_scan_add(int* __restrict__ offs, const int* __restrict__ blksum,
    int* __restrict__ bincur, int nelem, int n){
  int i = blockIdx.x*256 + threadIdx.x;
  if (i < nelem){
    int v = offs[i] + blksum[blockIdx.x];
    offs[i] = v;
    if (i < n && (i & ((1<<NBSH)-1)) == 0) bincur[i >> NBSH] = v;
  }
}

// ---------------- weight folding, BOTH layers in one launch (block = layer) ----------------
// Also zeroes gmax, deg, and the rec2 slack region (sid 0 -> safe prefetch gathers in k_agg).
__global__ __launch_bounds__(512) void k_prep(
    const float* __restrict__ W1, const float* __restrict__ as1, const float* __restrict__ ad1,
    const float* __restrict__ b1, const float* __restrict__ lb1, const float* __restrict__ lW1,
    const float* __restrict__ W2, const float* __restrict__ as2, const float* __restrict__ ad2,
    const float* __restrict__ b2, const float* __restrict__ lb2, const float* __restrict__ lW2,
    short* __restrict__ wbigT, short* __restrict__ wattBsw, float* __restrict__ bcomb,
    unsigned* __restrict__ gmax, int4* __restrict__ rec2, int* __restrict__ deg, int E, int n){
  int L = blockIdx.x;
  const float* W   = L ? W2  : W1;
  const float* asv = L ? as2 : as1;
  const float* adv = L ? ad2 : ad1;
  const float* b   = L ? b2  : b1;
  const float* lb  = L ? lb2 : lb1;
  const float* lW  = L ? lW2 : lW1;
  short* wbT = wbigT  + (size_t)L*64*328;
  short* wsw = wattBsw + L*1024;
  float* bc  = bcomb  + L*64;
  __shared__ float watt[512];
  int t = threadIdx.x;
  { int j = t >> 6, k = t & 63, h = j & 3;
    const float* att = (j < 4) ? asv : adv;
    float s = 0.f;
    for (int c = 0; c < 64; ++c) s += W[k*256 + h*64 + c] * att[h*64 + c];
    watt[j*64 + k] = s; }
  if (t < 8) gmax[t] = 0u;          // both blocks write 0 -> benign
  if (t < 64) bc[t] = b[t] + lb[t];
  if (L == 0 && t < 16){ int4 z; z.x = 0; z.y = 0; z.z = 0; z.w = 0; rec2[E + t] = z; }
  for (int i = L*512 + t; i < n; i += 1024) deg[i] = 0;    // replaces hipMemsetAsync
  __syncthreads();
  for (int i = t; i < 1024; i += 512){
    int step = i >> 9, lane = (i >> 3) & 63, j = i & 7;
    int col = lane & 15, q = lane >> 4, k = step*32 + q*8 + j;
    float v = (col < 8) ? watt[col*64 + k] : 0.f;
    wsw[i] = (short)bf16rne(v);
  }
  for (int i = t; i < 64*328; i += 512){
    int c = i / 328, q = i - c*328;
    float val = 0.f;
    if (q < 256){ int hh = q >> 6, cin = q & 63; val = 0.25f * W[cin*256 + hh*64 + c]; }
    else if (q < 320){ int kk = q - 256; val = lW[kk*64 + c]; }
    wbT[i] = (short)bf16rne(val);
  }
}

// ---------------- MFMA attention scalars: asrc/adst = feat @ wattB; + xbf emit (L1) + gmax ----
__global__ __launch_bounds__(256) void k_att(const float* __restrict__ featF,
    const unsigned short* __restrict__ featB, const short* __restrict__ wattBsw,
    float* __restrict__ asrc, float* __restrict__ adst, unsigned short* __restrict__ xbf,
    unsigned* __restrict__ gmax, int n){
  __shared__ unsigned shm[4];
  int t = threadIdx.x;
  if (t < 4) shm[t] = 0u;
  __syncthreads();
  int lane = t & 63, w = t >> 6;
  int nodebase = blockIdx.x*64 + w*16;
  int row16 = lane & 15, q = lane >> 4;
  int rowc = nodebase + row16; if (rowc > n-1) rowc = n-1;   // clamp: duplicate work, benign stores
  short8 a0, a1;
  if (featF){
    const float* fp = featF + (size_t)rowc*64;
    float4 c00 = *(const float4*)(fp + q*8);
    float4 c01 = *(const float4*)(fp + q*8 + 4);
    float4 c10 = *(const float4*)(fp + 32 + q*8);
    float4 c11 = *(const float4*)(fp + 32 + q*8 + 4);
    a0[0]=(short)bf16rne(c00.x); a0[1]=(short)bf16rne(c00.y); a0[2]=(short)bf16rne(c00.z); a0[3]=(short)bf16rne(c00.w);
    a0[4]=(short)bf16rne(c01.x); a0[5]=(short)bf16rne(c01.y); a0[6]=(short)bf16rne(c01.z); a0[7]=(short)bf16rne(c01.w);
    a1[0]=(short)bf16rne(c10.x); a1[1]=(short)bf16rne(c10.y); a1[2]=(short)bf16rne(c10.z); a1[3]=(short)bf16rne(c10.w);
    a1[4]=(short)bf16rne(c11.x); a1[5]=(short)bf16rne(c11.y); a1[6]=(short)bf16rne(c11.z); a1[7]=(short)bf16rne(c11.w);
    *(short8*)(xbf + (size_t)rowc*64 + q*8) = a0;
    *(short8*)(xbf + (size_t)rowc*64 + 32 + q*8) = a1;
  } else {
    a0 = *(const short8*)(featB + (size_t)rowc*64 + q*8);
    a1 = *(const short8*)(featB + (size_t)rowc*64 + 32 + q*8);
  }
  short8 b0 = *(const short8*)(wattBsw + lane*8);
  short8 b1 = *(const short8*)(wattBsw + 512 + lane*8);
  f32x4 acc = {0.f,0.f,0.f,0.f};
  acc = __builtin_amdgcn_mfma_f32_16x16x32_bf16(a0, b0, acc, 0, 0, 0);
  acc = __builtin_amdgcn_mfma_f32_16x16x32_bf16(a1, b1, acc, 0, 0, 0);
  int c = lane & 15;
  int rbase = nodebase + q*4;
  if (c < 8){
    float* dstp = (c < 4) ? asrc : adst;
    int hh = c & 3;
    float vmax = -INFINITY;
    #pragma unroll
    for (int r = 0; r < 4; ++r){
      int rr = rbase + r; if (rr > n-1) rr = n-1;
      dstp[(size_t)rr*4 + hh] = acc[r];
      vmax = fmaxf(vmax, acc[r]);
    }
    if (c < 4) atomicMax(&shm[hh], fenc(vmax));
  }
  __syncthreads();
  if (t < 4) atomicMax(gmax + t, shm[t]);
}

// ------ pass 1: fused per-edge probabilities + BINNED scatter (chunk-contiguous) ------
__global__ __launch_bounds__(256) void k_scatbin(const int* __restrict__ src, const int* __restrict__ dst,
    const float* __restrict__ asrc, const float* __restrict__ adst,
    int* __restrict__ bincur, const unsigned* __restrict__ gmax,
    int4* __restrict__ rec1, int E){
  __shared__ int hcnt[MAXBIN];
  __shared__ int hbase[MAXBIN];
  int t = threadIdx.x;
  int base = blockIdx.x * 4096 + t;
  if (t < MAXBIN) hcnt[t] = 0;
  __syncthreads();
  int rank[16];
  #pragma unroll
  for (int k = 0; k < 16; ++k){
    int e = base + k*256;
    rank[k] = 0;
    if (e < E){
      int d = dst[e];
      rank[k] = atomicAdd(&hcnt[d >> NBSH], 1);
    }
  }
  __syncthreads();
  if (t < MAXBIN && hcnt[t] > 0) hbase[t] = atomicAdd(&bincur[t], hcnt[t]);
  __syncthreads();
  float gm0 = fdec(gmax[0]), gm1 = fdec(gmax[1]), gm2 = fdec(gmax[2]), gm3 = fdec(gmax[3]);
  #pragma unroll
  for (int k = 0; k < 16; ++k){
    int e = base + k*256;
    if (e < E){
      int d = dst[e], s = src[e];
      float4 as = *(const float4*)(asrc + (size_t)s*4);
      float4 ad = *(const float4*)(adst + (size_t)d*4);
      float g0 = gm0 + ad.x; g0 = fmaxf(g0, 0.2f*g0);
      float g1 = gm1 + ad.y; g1 = fmaxf(g1, 0.2f*g1);
      float g2 = gm2 + ad.z; g2 = fmaxf(g2, 0.2f*g2);
      float g3 = gm3 + ad.w; g3 = fmaxf(g3, 0.2f*g3);
      float l0 = as.x + ad.x; l0 = fmaxf(l0, 0.2f*l0);
      float l1 = as.y + ad.y; l1 = fmaxf(l1, 0.2f*l1);
      float l2 = as.z + ad.z; l2 = fmaxf(l2, 0.2f*l2);
      float l3 = as.w + ad.w; l3 = fmaxf(l3, 0.2f*l3);
      unsigned lo = (unsigned)bf16rne(__expf(l0 - g0)) | ((unsigned)bf16rne(__expf(l1 - g1)) << 16);
      unsigned hi = (unsigned)bf16rne(__expf(l2 - g2)) | ((unsigned)bf16rne(__expf(l3 - g3)) << 16);
      int4 rv; rv.x = (int)lo; rv.y = (int)hi; rv.z = s; rv.w = d;
      rec1[hbase[d >> NBSH] + rank[k]] = rv;
    }
  }
}

// ------ pass 2: bin window -> exact CSR position (one block OWNS one bin window) ------
__global__ __launch_bounds__(256) void k_place(const int4* __restrict__ rec1,
    const int* __restrict__ offs, int4* __restrict__ rec2, int n){
  __shared__ int cur[1 << NBSH];
  int t = threadIdx.x;
  int nodebase = blockIdx.x << NBSH;
  int nodeend = nodebase + (1 << NBSH); if (nodeend > n) nodeend = n;
  for (int i = t; i < (1 << NBSH); i += 256) cur[i] = 0;
  __syncthreads();
  int winlo = offs[nodebase], winhi = offs[nodeend];
  for (int i = winlo + t; i < winhi; i += 256){
    int4 r = rec1[i];
    int d = r.w;
    int pos = offs[d] + atomicAdd(&cur[d - nodebase], 1);
    rec2[pos] = r;
  }
}

// ---------------- layer-2 probabilities: sequential in-place rewrite of rec2.p ----------------
__global__ __launch_bounds__(256) void k_edge2(int4* __restrict__ rec,
    const float* __restrict__ asrc, const float* __restrict__ adst,
    const unsigned* __restrict__ gmax, int E){
  int i = blockIdx.x*256 + threadIdx.x;
  if (i >= E) return;
  int4 r = rec[i];
  int s = r.z, d = r.w;
  float4 as = *(const float4*)(asrc + (size_t)s*4);
  float4 ad = *(const float4*)(adst + (size_t)d*4);   // dst-sorted -> near-sequential
  float g0 = fdec(gmax[0]) + ad.x; g0 = fmaxf(g0, 0.2f*g0);
  float g1 = fdec(gmax[1]) + ad.y; g1 = fmaxf(g1, 0.2f*g1);
  float g2 = fdec(gmax[2]) + ad.z; g2 = fmaxf(g2, 0.2f*g2);
  float g3 = fdec(gmax[3]) + ad.w; g3 = fmaxf(g3, 0.2f*g3);
  float l0 = as.x + ad.x; l0 = fmaxf(l0, 0.2f*l0);
  float l1 = as.y + ad.y; l1 = fmaxf(l1, 0.2f*l1);
  float l2 = as.z + ad.z; l2 = fmaxf(l2, 0.2f*l2);
  float l3 = as.w + ad.w; l3 = fmaxf(l3, 0.2f*l3);
  r.x = (int)((unsigned)bf16rne(__expf(l0 - g0)) | ((unsigned)bf16rne(__expf(l1 - g1)) << 16));
  r.y = (int)((unsigned)bf16rne(__expf(l2 - g2)) | ((unsigned)bf16rne(__expf(l3 - g3)) << 16));
  rec[i] = r;
}

// ------- edge aggregation: TWO nodes per wave over their COMBINED contiguous CSR range -------
// reA==rsB, so [rsA,reB) is one stream; per-edge A/B routing is a uniform s_cmp branch.
// Avg 32 edges/wave -> pipeline reaches steady state; fixed costs amortize over 2 nodes.
__global__ __launch_bounds__(64) void k_agg(const int4* __restrict__ rec,
    const int* __restrict__ offs, const unsigned short* __restrict__ xbf,
    short* __restrict__ Abf, int n){
  int vA = blockIdx.x*2;
  if (vA >= n) return;
  int vB = vA + 1;
  int lane = threadIdx.x & 63;
  int rs  = __builtin_amdgcn_readfirstlane(offs[vA]);
  int reA = __builtin_amdgcn_readfirstlane(offs[vA+1]);
  int reB = (vB < n) ? __builtin_amdgcn_readfirstlane(offs[vB+1]) : reA;
  int nrem = reB - rs;
  const int4* rp = rec + rs;
  float sA0=0.f,sA1=0.f,sA2=0.f,sA3=0.f, aA0=0.f,aA1=0.f,aA2=0.f,aA3=0.f;
  float sB0=0.f,sB1=0.f,sB2=0.f,sB3=0.f, aB0=0.f,aB1=0.f,aB2=0.f,aB3=0.f;

#define ACC(LO,HI,XU,IDX) { \
    float xc = __uint_as_float(((unsigned)(XU)) << 16); \
    float p0 = __uint_as_float((LO) << 16); \
    float p1 = __uint_as_float((LO) & 0xFFFF0000u); \
    float p2 = __uint_as_float((HI) << 16); \
    float p3 = __uint_as_float((HI) & 0xFFFF0000u); \
    if ((IDX) < reA){ \
      sA0 += p0; sA1 += p1; sA2 += p2; sA3 += p3; \
      aA0 = fmaf(p0, xc, aA0); aA1 = fmaf(p1, xc, aA1); \
      aA2 = fmaf(p2, xc, aA2); aA3 = fmaf(p3, xc, aA3); \
    } else { \
      sB0 += p0; sB1 += p1; sB2 += p2; sB3 += p3; \
      aB0 = fmaf(p0, xc, aB0); aB1 = fmaf(p1, xc, aB1); \
      aB2 = fmaf(p2, xc, aB2); aB3 = fmaf(p3, xc, aB3); \
    } }

  int nch = nrem >> 2;
  int c = 0;
  if (nch > 0){
    int4 R0[4], R1[4], T[4], U[4];
    unsigned xw0[4], xw1[4];
    #pragma unroll
    for (int j = 0; j < 4; ++j) R0[j] = rp[j];
    #pragma unroll
    for (int j = 0; j < 4; ++j) xw0[j] = xbf[(((size_t)(unsigned)R0[j].z)<<6)+lane];
    #pragma unroll
    for (int j = 0; j < 4; ++j) R1[j] = rp[4+j];
    for (; c + 1 < nch; c += 2){
      #pragma unroll
      for (int j = 0; j < 4; ++j) T[j] = rp[((c+2)<<2)+j];        // recs chunk c+2 (in flight)
      #pragma unroll
      for (int j = 0; j < 4; ++j) xw1[j] = xbf[(((size_t)(unsigned)R1[j].z)<<6)+lane]; // gathers c+1
      #pragma unroll
      for (int j = 0; j < 4; ++j) U[j] = rp[((c+3)<<2)+j];        // recs chunk c+3
      #pragma unroll
      for (int j = 0; j < 4; ++j) ACC((unsigned)R0[j].x, (unsigned)R0[j].y, xw0[j], rs+(c<<2)+j);
      #pragma unroll
      for (int j = 0; j < 4; ++j) R0[j] = T[j];
      #pragma unroll
      for (int j = 0; j < 4; ++j) xw0[j] = xbf[(((size_t)(unsigned)R0[j].z)<<6)+lane]; // gathers c+2
      #pragma unroll
      for (int j = 0; j < 4; ++j) ACC((unsigned)R1[j].x, (unsigned)R1[j].y, xw1[j], rs+((c+1)<<2)+j);
      #pragma unroll
      for (int j = 0; j < 4; ++j) R1[j] = U[j];
    }
    if (c < nch){   // odd final chunk sits in R0/xw0
      #pragma unroll
      for (int j = 0; j < 4; ++j) ACC((unsigned)R0[j].x, (unsigned)R0[j].y, xw0[j], rs+(c<<2)+j);
    }
  }
  for (int i = nch<<2; i < nrem; ++i){    // tail <=3 edges
    int4 t = rp[i];
    unsigned xt = xbf[(((size_t)(unsigned)t.z)<<6)+lane];
    ACC((unsigned)t.x, (unsigned)t.y, xt, rs+i);
  }
#undef ACC
  size_t baseA = (size_t)vA*256 + lane;
  Abf[baseA +   0] = (short)bf16rne(aA0 / (sA0 + 1e-16f));   // deg==0 -> 0, matches reference
  Abf[baseA +  64] = (short)bf16rne(aA1 / (sA1 + 1e-16f));
  Abf[baseA + 128] = (short)bf16rne(aA2 / (sA2 + 1e-16f));
  Abf[baseA + 192] = (short)bf16rne(aA3 / (sA3 + 1e-16f));
  if (vB < n){
    size_t baseB = (size_t)vB*256 + lane;
    Abf[baseB +   0] = (short)bf16rne(aB0 / (sB0 + 1e-16f));
    Abf[baseB +  64] = (short)bf16rne(aB1 / (sB1 + 1e-16f));
    Abf[baseB + 128] = (short)bf16rne(aB2 / (sB2 + 1e-16f));
    Abf[baseB + 192] = (short)bf16rne(aB3 / (sB3 + 1e-16f));
  }
}

// ---------------- MFMA epilogue: out = [Abf|xbf] @ B + bcomb ----------------
__global__ __launch_bounds__(256) void k_out(const short* __restrict__ Abf,
    const unsigned short* __restrict__ xbf, const short* __restrict__ wbigT,
    const float* __restrict__ bcomb, float* __restrict__ outF, unsigned short* __restrict__ outB, int n){
  __shared__ __align__(16) short sB[64*328];
  {
    const short8* gs = (const short8*)wbigT;
    short8* ls = (short8*)sB;
    for (int i = threadIdx.x; i < 64*328/8; i += 256) ls[i] = gs[i];
  }
  __syncthreads();
  int lane = threadIdx.x & 63, wid = threadIdx.x >> 6;
  int rowbase = blockIdx.x*64 + wid*16;
  int arow = rowbase + (lane & 15); if (arow > n-1) arow = n-1;
  int ksub = (lane >> 4) * 8;
  const short* ap = Abf + (size_t)arow*256 + ksub;
  const short* xp = (const short*)xbf + (size_t)arow*64 + ksub;
  const short* bp = sB + (lane & 15)*328 + ksub;
  f32x4 acc0 = {0.f,0.f,0.f,0.f}, acc1 = acc0, acc2 = acc0, acc3 = acc0;
  #pragma unroll
  for (int k0 = 0; k0 < 320; k0 += 32){
    short8 a  = (k0 < 256) ? *(const short8*)(ap + k0) : *(const short8*)(xp + (k0 - 256));
    short8 b0 = *(const short8*)(bp + k0);
    short8 b1 = *(const short8*)(bp + 16*328 + k0);
    short8 b2 = *(const short8*)(bp + 32*328 + k0);
    short8 b3 = *(const short8*)(bp + 48*328 + k0);
    acc0 = __builtin_amdgcn_mfma_f32_16x16x32_bf16(a, b0, acc0, 0, 0, 0);
    acc1 = __builtin_amdgcn_mfma_f32_16x16x32_bf16(a, b1, acc1, 0, 0, 0);
    acc2 = __builtin_amdgcn_mfma_f32_16x16x32_bf16(a, b2, acc2, 0, 0, 0);
    acc3 = __builtin_amdgcn_mfma_f32_16x16x32_bf16(a, b3, acc3, 0, 0, 0);
  }
  int ccol = lane & 15;
  int crow = rowbase + (lane >> 4)*4;
  float bb0 = bcomb[ 0 + ccol];
  float bb1 = bcomb[16 + ccol];
  float bb2 = bcomb[32 + ccol];
  float bb3 = bcomb[48 + ccol];
  #pragma unroll
  for (int r = 0; r < 4; ++r){
    int rr = crow + r;
    if (rr < n){
      float o0 = acc0[r] + bb0, o1 = acc1[r] + bb1, o2 = acc2[r] + bb2, o3 = acc3[r] + bb3;
      if (outB){
        unsigned short* orow = outB + (size_t)rr*64;
        orow[ 0 + ccol] = bf16rne(fmaxf(o0, 0.f));
        orow[16 + ccol] = bf16rne(fmaxf(o1, 0.f));
        orow[32 + ccol] = bf16rne(fmaxf(o2, 0.f));
        orow[48 + ccol] = bf16rne(fmaxf(o3, 0.f));
      } else {
        float* orow = outF + (size_t)rr*64;
        orow[ 0 + ccol] = o0;
        orow[16 + ccol] = o1;
        orow[32 + ccol] = o2;
        orow[48 + ccol] = o3;
      }
    }
  }
}

extern "C" void kernel_launch(void* const* d_in, const int* in_sizes, int n_in,
                              void* d_out, int out_size, void* d_ws, size_t ws_size,
                              hipStream_t stream){
  const float* x   = (const float*)d_in[0];
  const int*   ei  = (const int*)d_in[1];
  const float* W1  = (const float*)d_in[2];
  const float* as1 = (const float*)d_in[3];
  const float* ad1 = (const float*)d_in[4];
  const float* b1  = (const float*)d_in[5];
  const float* lW1 = (const float*)d_in[6];
  const float* lb1 = (const float*)d_in[7];
  const float* W2  = (const float*)d_in[8];
  const float* as2 = (const float*)d_in[9];
  const float* ad2 = (const float*)d_in[10];
  const float* b2  = (const float*)d_in[11];
  const float* lW2 = (const float*)d_in[12];
  const float* lb2 = (const float*)d_in[13];
  int N = in_sizes[0] / 64;
  int E = in_sizes[1] / 2;
  const int* srce = ei;
  const int* dste = ei + E;

  char* w = (char*)d_ws;
  size_t off = 0;
  auto alloc = [&](size_t bytes)->char*{
    char* p = w + off; off = (off + bytes + 255) & ~(size_t)255; return p;
  };
  int*      offs    = (int*)     alloc((size_t)(N+1)*4);
  int*      deg     = (int*)     alloc((size_t)N*4);
  int*      bincur  = (int*)     alloc(MAXBIN*4);
  int*      blksum  = (int*)     alloc(4096);
  int4*     rec1    = (int4*)    alloc((size_t)E*16);
  int4*     rec2    = (int4*)    alloc((size_t)(E+16)*16);   // +16 slack for pipeline overrun
  short*    wbigT   = (short*)   alloc((size_t)2*64*328*2);
  short*    wattBsw = (short*)   alloc(2*1024*2);
  float*    bcomb   = (float*)   alloc(2*64*4);
  unsigned* gmax    = (unsigned*)alloc(32);            // [0..3]=layer1, [4..7]=layer2
  float*    pasrc   = (float*)   alloc((size_t)N*16);
  float*    padst   = (float*)   alloc((size_t)N*16);
  short*    Abf     = (short*)   alloc((size_t)N*256*2);
  unsigned short* xbf1 = (unsigned short*)alloc((size_t)N*64*2);
  unsigned short* xbf2 = (unsigned short*)alloc((size_t)N*64*2);
  (void)ws_size; (void)n_in; (void)out_size;

  int gE = (E + 255)/256;
  int nelem = N + 1;
  int nb = (nelem + 255)/256;
  int gATT = (N + 63)/64;
  int gOUT = (N + 63)/64;
  int gSB  = (E + 4095)/4096;
  int nbin = (N + (1<<NBSH) - 1) >> NBSH;
  int gAGG = (N + 1)/2;
  float* outp = (float*)d_out;

  // weights for both layers + gmax/deg zeroing + rec2 slack init, one launch
  k_prep<<<2, 512, 0, stream>>>(W1, as1, ad1, b1, lb1, lW1,
                                W2, as2, ad2, b2, lb2, lW2,
                                wbigT, wattBsw, bcomb, gmax, rec2, deg, E, N);

  // CSR offsets (built once, reused by both layers); scan_add also seeds bincur
  k_hist<<<gE, 256, 0, stream>>>(dste, deg, E);
  k_scan_local<<<nb, 256, 0, stream>>>(deg, offs, blksum, nelem, N);
  k_scan_blk<<<1, 256, 0, stream>>>(blksum, nb);
  k_scan_add<<<nb, 256, 0, stream>>>(offs, blksum, bincur, nelem, N);

  // ----- layer 1 -----
  k_att <<<gATT, 256, 0, stream>>>(x, nullptr, wattBsw, pasrc, padst, xbf1, gmax, N);
  k_scatbin<<<gSB, 256, 0, stream>>>(srce, dste, pasrc, padst, bincur, gmax, rec1, E);
  k_place<<<nbin, 256, 0, stream>>>(rec1, offs, rec2, N);
  k_agg <<<gAGG, 64, 0, stream>>>(rec2, offs, xbf1, Abf, N);
  k_out <<<gOUT, 256, 0, stream>>>(Abf, xbf1, wbigT, bcomb, nullptr, xbf2, N);   // h = relu -> bf16

  // ----- layer 2 -----
  k_att <<<gATT, 256, 0, stream>>>(nullptr, xbf2, wattBsw + 1024, pasrc, padst, nullptr, gmax + 4, N);
  k_edge2<<<gE, 256, 0, stream>>>(rec2, pasrc, padst, gmax + 4, E);
  k_agg <<<gAGG, 64, 0, stream>>>(rec2, offs, xbf2, Abf, N);
  k_out <<<gOUT, 256, 0, stream>>>(Abf, xbf2, wbigT + 64*328, bcomb + 64, outp, nullptr, N);
}

// Round 14
// 233.820 us; speedup vs baseline: 1.0805x; 1.0805x over previous
//
#include <hip/hip_runtime.h>
#include <math.h>

typedef __attribute__((ext_vector_type(8))) short short8;
typedef __attribute__((ext_vector_type(4))) float f32x4;

#define NBSH 9          // 512 nodes per bin
#define MAXBIN 128

__device__ inline unsigned fenc(float f){
  unsigned u = __float_as_uint(f);
  return u ^ ((u >> 31) ? 0xFFFFFFFFu : 0x80000000u);
}
__device__ inline float fdec(unsigned k){
  unsigned u = (k & 0x80000000u) ? (k ^ 0x80000000u) : ~k;
  return __uint_as_float(u);
}
__device__ inline unsigned short bf16rne(float f){
  unsigned u = __float_as_uint(f);
  return (unsigned short)((u + 0x7FFFu + ((u >> 16) & 1u)) >> 16);
}

// ---------------- CSR build ----------------
__global__ __launch_bounds__(256) void k_hist(const int* __restrict__ dst, int* __restrict__ deg, int E){
  int e = blockIdx.x*256 + threadIdx.x;
  if (e < E) atomicAdd(&deg[dst[e]], 1);
}

__global__ __launch_bounds__(256) void k_scan_local(const int* __restrict__ deg, int* __restrict__ offs,
    int* __restrict__ blksum, int nelem, int ndeg){
  __shared__ int sh[256];
  int t = threadIdx.x;
  int i = blockIdx.x*256 + t;
  int v = (i < ndeg) ? deg[i] : 0;
  sh[t] = v; __syncthreads();
  for (int d = 1; d < 256; d <<= 1){
    int add = (t >= d) ? sh[t-d] : 0; __syncthreads();
    sh[t] += add; __syncthreads();
  }
  if (i < nelem) offs[i] = sh[t] - v;   // exclusive
  if (t == 255) blksum[blockIdx.x] = sh[t];
}

__global__ __launch_bounds__(256) void k_scan_blk(int* __restrict__ blksum, int nb){
  __shared__ int sh[256];
  int t = threadIdx.x;
  int running = 0;
  for (int base = 0; base < nb; base += 256){
    int v = (base+t < nb) ? blksum[base+t] : 0;
    __syncthreads();
    sh[t] = v; __syncthreads();
    for (int d = 1; d < 256; d <<= 1){
      int add = (t >= d) ? sh[t-d] : 0; __syncthreads();
      sh[t] += add; __syncthreads();
    }
    if (base+t < nb) blksum[base+t] = running + sh[t] - v;
    running += sh[255];
  }
}

// also seeds bincur[b] = offs[b<<NBSH]  (bin regions are CSR sub-ranges)
__global__ __launch_bounds__(256) void k_scan_add(int* __restrict__ offs, const int* __restrict__ blksum,
    int* __restrict__ bincur, int nelem, int n){
  int i = blockIdx.x*256 + threadIdx.x;
  if (i < nelem){
    int v = offs[i] + blksum[blockIdx.x];
    offs[i] = v;
    if (i < n && (i & ((1<<NBSH)-1)) == 0) bincur[i >> NBSH] = v;
  }
}

// ---------------- weight folding, BOTH layers in one launch (block = layer) ----------------
// Also zeroes gmax, deg, and the rec2 slack region (sid 0 -> safe prefetch gathers in k_agg).
__global__ __launch_bounds__(512) void k_prep(
    const float* __restrict__ W1, const float* __restrict__ as1, const float* __restrict__ ad1,
    const float* __restrict__ b1, const float* __restrict__ lb1, const float* __restrict__ lW1,
    const float* __restrict__ W2, const float* __restrict__ as2, const float* __restrict__ ad2,
    const float* __restrict__ b2, const float* __restrict__ lb2, const float* __restrict__ lW2,
    short* __restrict__ wbigT, short* __restrict__ wattBsw, float* __restrict__ bcomb,
    unsigned* __restrict__ gmax, int4* __restrict__ rec2, int* __restrict__ deg, int E, int n){
  int L = blockIdx.x;
  const float* W   = L ? W2  : W1;
  const float* asv = L ? as2 : as1;
  const float* adv = L ? ad2 : ad1;
  const float* b   = L ? b2  : b1;
  const float* lb  = L ? lb2 : lb1;
  const float* lW  = L ? lW2 : lW1;
  short* wbT = wbigT  + (size_t)L*64*328;
  short* wsw = wattBsw + L*1024;
  float* bc  = bcomb  + L*64;
  __shared__ float watt[512];
  int t = threadIdx.x;
  { int j = t >> 6, k = t & 63, h = j & 3;
    const float* att = (j < 4) ? asv : adv;
    float s = 0.f;
    for (int c = 0; c < 64; ++c) s += W[k*256 + h*64 + c] * att[h*64 + c];
    watt[j*64 + k] = s; }
  if (t < 8) gmax[t] = 0u;          // both blocks write 0 -> benign
  if (t < 64) bc[t] = b[t] + lb[t];
  if (L == 0 && t < 16){ int4 z; z.x = 0; z.y = 0; z.z = 0; z.w = 0; rec2[E + t] = z; }
  for (int i = L*512 + t; i < n; i += 1024) deg[i] = 0;    // replaces hipMemsetAsync
  __syncthreads();
  for (int i = t; i < 1024; i += 512){
    int step = i >> 9, lane = (i >> 3) & 63, j = i & 7;
    int col = lane & 15, q = lane >> 4, k = step*32 + q*8 + j;
    float v = (col < 8) ? watt[col*64 + k] : 0.f;
    wsw[i] = (short)bf16rne(v);
  }
  for (int i = t; i < 64*328; i += 512){
    int c = i / 328, q = i - c*328;
    float val = 0.f;
    if (q < 256){ int hh = q >> 6, cin = q & 63; val = 0.25f * W[cin*256 + hh*64 + c]; }
    else if (q < 320){ int kk = q - 256; val = lW[kk*64 + c]; }
    wbT[i] = (short)bf16rne(val);
  }
}

// ---------------- MFMA attention scalars: asrc/adst = feat @ wattB; + xbf emit (L1) + gmax ----
__global__ __launch_bounds__(256) void k_att(const float* __restrict__ featF,
    const unsigned short* __restrict__ featB, const short* __restrict__ wattBsw,
    float* __restrict__ asrc, float* __restrict__ adst, unsigned short* __restrict__ xbf,
    unsigned* __restrict__ gmax, int n){
  __shared__ unsigned shm[4];
  int t = threadIdx.x;
  if (t < 4) shm[t] = 0u;
  __syncthreads();
  int lane = t & 63, w = t >> 6;
  int nodebase = blockIdx.x*64 + w*16;
  int row16 = lane & 15, q = lane >> 4;
  int rowc = nodebase + row16; if (rowc > n-1) rowc = n-1;   // clamp: duplicate work, benign stores
  short8 a0, a1;
  if (featF){
    const float* fp = featF + (size_t)rowc*64;
    float4 c00 = *(const float4*)(fp + q*8);
    float4 c01 = *(const float4*)(fp + q*8 + 4);
    float4 c10 = *(const float4*)(fp + 32 + q*8);
    float4 c11 = *(const float4*)(fp + 32 + q*8 + 4);
    a0[0]=(short)bf16rne(c00.x); a0[1]=(short)bf16rne(c00.y); a0[2]=(short)bf16rne(c00.z); a0[3]=(short)bf16rne(c00.w);
    a0[4]=(short)bf16rne(c01.x); a0[5]=(short)bf16rne(c01.y); a0[6]=(short)bf16rne(c01.z); a0[7]=(short)bf16rne(c01.w);
    a1[0]=(short)bf16rne(c10.x); a1[1]=(short)bf16rne(c10.y); a1[2]=(short)bf16rne(c10.z); a1[3]=(short)bf16rne(c10.w);
    a1[4]=(short)bf16rne(c11.x); a1[5]=(short)bf16rne(c11.y); a1[6]=(short)bf16rne(c11.z); a1[7]=(short)bf16rne(c11.w);
    *(short8*)(xbf + (size_t)rowc*64 + q*8) = a0;
    *(short8*)(xbf + (size_t)rowc*64 + 32 + q*8) = a1;
  } else {
    a0 = *(const short8*)(featB + (size_t)rowc*64 + q*8);
    a1 = *(const short8*)(featB + (size_t)rowc*64 + 32 + q*8);
  }
  short8 b0 = *(const short8*)(wattBsw + lane*8);
  short8 b1 = *(const short8*)(wattBsw + 512 + lane*8);
  f32x4 acc = {0.f,0.f,0.f,0.f};
  acc = __builtin_amdgcn_mfma_f32_16x16x32_bf16(a0, b0, acc, 0, 0, 0);
  acc = __builtin_amdgcn_mfma_f32_16x16x32_bf16(a1, b1, acc, 0, 0, 0);
  int c = lane & 15;
  int rbase = nodebase + q*4;
  if (c < 8){
    float* dstp = (c < 4) ? asrc : adst;
    int hh = c & 3;
    float vmax = -INFINITY;
    #pragma unroll
    for (int r = 0; r < 4; ++r){
      int rr = rbase + r; if (rr > n-1) rr = n-1;
      dstp[(size_t)rr*4 + hh] = acc[r];
      vmax = fmaxf(vmax, acc[r]);
    }
    if (c < 4) atomicMax(&shm[hh], fenc(vmax));
  }
  __syncthreads();
  if (t < 4) atomicMax(gmax + t, shm[t]);
}

// ------ pass 1: fused per-edge probabilities + BINNED scatter (chunk-contiguous) ------
__global__ __launch_bounds__(256) void k_scatbin(const int* __restrict__ src, const int* __restrict__ dst,
    const float* __restrict__ asrc, const float* __restrict__ adst,
    int* __restrict__ bincur, const unsigned* __restrict__ gmax,
    int4* __restrict__ rec1, int E){
  __shared__ int hcnt[MAXBIN];
  __shared__ int hbase[MAXBIN];
  int t = threadIdx.x;
  int base = blockIdx.x * 4096 + t;
  if (t < MAXBIN) hcnt[t] = 0;
  __syncthreads();
  int rank[16];
  #pragma unroll
  for (int k = 0; k < 16; ++k){
    int e = base + k*256;
    rank[k] = 0;
    if (e < E){
      int d = dst[e];
      rank[k] = atomicAdd(&hcnt[d >> NBSH], 1);
    }
  }
  __syncthreads();
  if (t < MAXBIN && hcnt[t] > 0) hbase[t] = atomicAdd(&bincur[t], hcnt[t]);
  __syncthreads();
  float gm0 = fdec(gmax[0]), gm1 = fdec(gmax[1]), gm2 = fdec(gmax[2]), gm3 = fdec(gmax[3]);
  #pragma unroll
  for (int k = 0; k < 16; ++k){
    int e = base + k*256;
    if (e < E){
      int d = dst[e], s = src[e];
      float4 as = *(const float4*)(asrc + (size_t)s*4);
      float4 ad = *(const float4*)(adst + (size_t)d*4);
      float g0 = gm0 + ad.x; g0 = fmaxf(g0, 0.2f*g0);
      float g1 = gm1 + ad.y; g1 = fmaxf(g1, 0.2f*g1);
      float g2 = gm2 + ad.z; g2 = fmaxf(g2, 0.2f*g2);
      float g3 = gm3 + ad.w; g3 = fmaxf(g3, 0.2f*g3);
      float l0 = as.x + ad.x; l0 = fmaxf(l0, 0.2f*l0);
      float l1 = as.y + ad.y; l1 = fmaxf(l1, 0.2f*l1);
      float l2 = as.z + ad.z; l2 = fmaxf(l2, 0.2f*l2);
      float l3 = as.w + ad.w; l3 = fmaxf(l3, 0.2f*l3);
      unsigned lo = (unsigned)bf16rne(__expf(l0 - g0)) | ((unsigned)bf16rne(__expf(l1 - g1)) << 16);
      unsigned hi = (unsigned)bf16rne(__expf(l2 - g2)) | ((unsigned)bf16rne(__expf(l3 - g3)) << 16);
      int4 rv; rv.x = (int)lo; rv.y = (int)hi; rv.z = s; rv.w = d;
      rec1[hbase[d >> NBSH] + rank[k]] = rv;
    }
  }
}

// ------ pass 2: bin window -> exact CSR position (one block OWNS one bin window) ------
__global__ __launch_bounds__(256) void k_place(const int4* __restrict__ rec1,
    const int* __restrict__ offs, int4* __restrict__ rec2, int n){
  __shared__ int cur[1 << NBSH];
  int t = threadIdx.x;
  int nodebase = blockIdx.x << NBSH;
  int nodeend = nodebase + (1 << NBSH); if (nodeend > n) nodeend = n;
  for (int i = t; i < (1 << NBSH); i += 256) cur[i] = 0;
  __syncthreads();
  int winlo = offs[nodebase], winhi = offs[nodeend];
  for (int i = winlo + t; i < winhi; i += 256){
    int4 r = rec1[i];
    int d = r.w;
    int pos = offs[d] + atomicAdd(&cur[d - nodebase], 1);
    rec2[pos] = r;
  }
}

// ---------------- layer-2 probabilities: sequential in-place rewrite of rec2.p ----------------
__global__ __launch_bounds__(256) void k_edge2(int4* __restrict__ rec,
    const float* __restrict__ asrc, const float* __restrict__ adst,
    const unsigned* __restrict__ gmax, int E){
  int i = blockIdx.x*256 + threadIdx.x;
  if (i >= E) return;
  int4 r = rec[i];
  int s = r.z, d = r.w;
  float4 as = *(const float4*)(asrc + (size_t)s*4);
  float4 ad = *(const float4*)(adst + (size_t)d*4);   // dst-sorted -> near-sequential
  float g0 = fdec(gmax[0]) + ad.x; g0 = fmaxf(g0, 0.2f*g0);
  float g1 = fdec(gmax[1]) + ad.y; g1 = fmaxf(g1, 0.2f*g1);
  float g2 = fdec(gmax[2]) + ad.z; g2 = fmaxf(g2, 0.2f*g2);
  float g3 = fdec(gmax[3]) + ad.w; g3 = fmaxf(g3, 0.2f*g3);
  float l0 = as.x + ad.x; l0 = fmaxf(l0, 0.2f*l0);
  float l1 = as.y + ad.y; l1 = fmaxf(l1, 0.2f*l1);
  float l2 = as.z + ad.z; l2 = fmaxf(l2, 0.2f*l2);
  float l3 = as.w + ad.w; l3 = fmaxf(l3, 0.2f*l3);
  r.x = (int)((unsigned)bf16rne(__expf(l0 - g0)) | ((unsigned)bf16rne(__expf(l1 - g1)) << 16));
  r.y = (int)((unsigned)bf16rne(__expf(l2 - g2)) | ((unsigned)bf16rne(__expf(l3 - g3)) << 16));
  rec[i] = r;
}

// ------- edge aggregation: 4 waves/block, ONE NODE PER WAVE, scalar rec path --------
// readfirstlane(offs[v]) yields per-wave SGPRs even though v is wid-derived, so the rec
// stream stays on the s_load/SALU path while occupancy is no longer workgroup-slot-capped.
__global__ __launch_bounds__(256) void k_agg(const int4* __restrict__ rec,
    const int* __restrict__ offs, const unsigned short* __restrict__ xbf,
    short* __restrict__ Abf, int n){
  int wid = threadIdx.x >> 6;
  int lane = threadIdx.x & 63;
  int v = blockIdx.x*4 + wid;
  if (v >= n) return;
  int rs = __builtin_amdgcn_readfirstlane(offs[v]);
  int re = __builtin_amdgcn_readfirstlane(offs[v+1]);
  int nrem = re - rs;
  const int4* rp = rec + rs;
  float s0=0.f,s1=0.f,s2=0.f,s3=0.f;
  float a0=0.f,a1=0.f,a2=0.f,a3=0.f;

#define ACC(LO,HI,XU) { \
    float xc = __uint_as_float(((unsigned)(XU)) << 16); \
    float p0 = __uint_as_float((LO) << 16); \
    float p1 = __uint_as_float((LO) & 0xFFFF0000u); \
    float p2 = __uint_as_float((HI) << 16); \
    float p3 = __uint_as_float((HI) & 0xFFFF0000u); \
    s0 += p0; s1 += p1; s2 += p2; s3 += p3; \
    a0 = fmaf(p0, xc, a0); a1 = fmaf(p1, xc, a1); \
    a2 = fmaf(p2, xc, a2); a3 = fmaf(p3, xc, a3); }

  int nch = nrem >> 2;
  if (nch > 0){
    int4 R0[4], R1[4], T[4], U[4];
    unsigned xw0[4], xw1[4];
    #pragma unroll
    for (int j = 0; j < 4; ++j) R0[j] = rp[j];
    #pragma unroll
    for (int j = 0; j < 4; ++j) xw0[j] = xbf[(((size_t)(unsigned)R0[j].z)<<6)+lane];
    #pragma unroll
    for (int j = 0; j < 4; ++j) R1[j] = rp[4+j];
    int c = 0;
    for (; c + 1 < nch; c += 2){
      #pragma unroll
      for (int j = 0; j < 4; ++j) T[j] = rp[((c+2)<<2)+j];        // recs chunk c+2 (in flight)
      #pragma unroll
      for (int j = 0; j < 4; ++j) xw1[j] = xbf[(((size_t)(unsigned)R1[j].z)<<6)+lane]; // gathers c+1
      #pragma unroll
      for (int j = 0; j < 4; ++j) U[j] = rp[((c+3)<<2)+j];        // recs chunk c+3
      #pragma unroll
      for (int j = 0; j < 4; ++j) ACC((unsigned)R0[j].x, (unsigned)R0[j].y, xw0[j]);   // compute c
      #pragma unroll
      for (int j = 0; j < 4; ++j) R0[j] = T[j];
      #pragma unroll
      for (int j = 0; j < 4; ++j) xw0[j] = xbf[(((size_t)(unsigned)R0[j].z)<<6)+lane]; // gathers c+2
      #pragma unroll
      for (int j = 0; j < 4; ++j) ACC((unsigned)R1[j].x, (unsigned)R1[j].y, xw1[j]);   // compute c+1
      #pragma unroll
      for (int j = 0; j < 4; ++j) R1[j] = U[j];
    }
    if (c < nch){   // odd final chunk sits in R0/xw0
      #pragma unroll
      for (int j = 0; j < 4; ++j) ACC((unsigned)R0[j].x, (unsigned)R0[j].y, xw0[j]);
    }
  }
  for (int i = nch<<2; i < nrem; ++i){    // tail <=3 edges
    int4 t = rp[i];
    unsigned xt = xbf[(((size_t)(unsigned)t.z)<<6)+lane];
    ACC((unsigned)t.x, (unsigned)t.y, xt);
  }
#undef ACC
  size_t base = (size_t)v*256 + lane;
  Abf[base +   0] = (short)bf16rne(a0 / (s0 + 1e-16f));   // deg==0 -> 0, matches reference
  Abf[base +  64] = (short)bf16rne(a1 / (s1 + 1e-16f));
  Abf[base + 128] = (short)bf16rne(a2 / (s2 + 1e-16f));
  Abf[base + 192] = (short)bf16rne(a3 / (s3 + 1e-16f));
}

// ---------------- MFMA epilogue: out = [Abf|xbf] @ B + bcomb ----------------
__global__ __launch_bounds__(256) void k_out(const short* __restrict__ Abf,
    const unsigned short* __restrict__ xbf, const short* __restrict__ wbigT,
    const float* __restrict__ bcomb, float* __restrict__ outF, unsigned short* __restrict__ outB, int n){
  __shared__ __align__(16) short sB[64*328];
  {
    const short8* gs = (const short8*)wbigT;
    short8* ls = (short8*)sB;
    for (int i = threadIdx.x; i < 64*328/8; i += 256) ls[i] = gs[i];
  }
  __syncthreads();
  int lane = threadIdx.x & 63, wid = threadIdx.x >> 6;
  int rowbase = blockIdx.x*64 + wid*16;
  int arow = rowbase + (lane & 15); if (arow > n-1) arow = n-1;
  int ksub = (lane >> 4) * 8;
  const short* ap = Abf + (size_t)arow*256 + ksub;
  const short* xp = (const short*)xbf + (size_t)arow*64 + ksub;
  const short* bp = sB + (lane & 15)*328 + ksub;
  f32x4 acc0 = {0.f,0.f,0.f,0.f}, acc1 = acc0, acc2 = acc0, acc3 = acc0;
  #pragma unroll
  for (int k0 = 0; k0 < 320; k0 += 32){
    short8 a  = (k0 < 256) ? *(const short8*)(ap + k0) : *(const short8*)(xp + (k0 - 256));
    short8 b0 = *(const short8*)(bp + k0);
    short8 b1 = *(const short8*)(bp + 16*328 + k0);
    short8 b2 = *(const short8*)(bp + 32*328 + k0);
    short8 b3 = *(const short8*)(bp + 48*328 + k0);
    acc0 = __builtin_amdgcn_mfma_f32_16x16x32_bf16(a, b0, acc0, 0, 0, 0);
    acc1 = __builtin_amdgcn_mfma_f32_16x16x32_bf16(a, b1, acc1, 0, 0, 0);
    acc2 = __builtin_amdgcn_mfma_f32_16x16x32_bf16(a, b2, acc2, 0, 0, 0);
    acc3 = __builtin_amdgcn_mfma_f32_16x16x32_bf16(a, b3, acc3, 0, 0, 0);
  }
  int ccol = lane & 15;
  int crow = rowbase + (lane >> 4)*4;
  float bb0 = bcomb[ 0 + ccol];
  float bb1 = bcomb[16 + ccol];
  float bb2 = bcomb[32 + ccol];
  float bb3 = bcomb[48 + ccol];
  #pragma unroll
  for (int r = 0; r < 4; ++r){
    int rr = crow + r;
    if (rr < n){
      float o0 = acc0[r] + bb0, o1 = acc1[r] + bb1, o2 = acc2[r] + bb2, o3 = acc3[r] + bb3;
      if (outB){
        unsigned short* orow = outB + (size_t)rr*64;
        orow[ 0 + ccol] = bf16rne(fmaxf(o0, 0.f));
        orow[16 + ccol] = bf16rne(fmaxf(o1, 0.f));
        orow[32 + ccol] = bf16rne(fmaxf(o2, 0.f));
        orow[48 + ccol] = bf16rne(fmaxf(o3, 0.f));
      } else {
        float* orow = outF + (size_t)rr*64;
        orow[ 0 + ccol] = o0;
        orow[16 + ccol] = o1;
        orow[32 + ccol] = o2;
        orow[48 + ccol] = o3;
      }
    }
  }
}

extern "C" void kernel_launch(void* const* d_in, const int* in_sizes, int n_in,
                              void* d_out, int out_size, void* d_ws, size_t ws_size,
                              hipStream_t stream){
  const float* x   = (const float*)d_in[0];
  const int*   ei  = (const int*)d_in[1];
  const float* W1  = (const float*)d_in[2];
  const float* as1 = (const float*)d_in[3];
  const float* ad1 = (const float*)d_in[4];
  const float* b1  = (const float*)d_in[5];
  const float* lW1 = (const float*)d_in[6];
  const float* lb1 = (const float*)d_in[7];
  const float* W2  = (const float*)d_in[8];
  const float* as2 = (const float*)d_in[9];
  const float* ad2 = (const float*)d_in[10];
  const float* b2  = (const float*)d_in[11];
  const float* lW2 = (const float*)d_in[12];
  const float* lb2 = (const float*)d_in[13];
  int N = in_sizes[0] / 64;
  int E = in_sizes[1] / 2;
  const int* srce = ei;
  const int* dste = ei + E;

  char* w = (char*)d_ws;
  size_t off = 0;
  auto alloc = [&](size_t bytes)->char*{
    char* p = w + off; off = (off + bytes + 255) & ~(size_t)255; return p;
  };
  int*      offs    = (int*)     alloc((size_t)(N+1)*4);
  int*      deg     = (int*)     alloc((size_t)N*4);
  int*      bincur  = (int*)     alloc(MAXBIN*4);
  int*      blksum  = (int*)     alloc(4096);
  int4*     rec1    = (int4*)    alloc((size_t)E*16);
  int4*     rec2    = (int4*)    alloc((size_t)(E+16)*16);   // +16 slack for pipeline overrun
  short*    wbigT   = (short*)   alloc((size_t)2*64*328*2);
  short*    wattBsw = (short*)   alloc(2*1024*2);
  float*    bcomb   = (float*)   alloc(2*64*4);
  unsigned* gmax    = (unsigned*)alloc(32);            // [0..3]=layer1, [4..7]=layer2
  float*    pasrc   = (float*)   alloc((size_t)N*16);
  float*    padst   = (float*)   alloc((size_t)N*16);
  short*    Abf     = (short*)   alloc((size_t)N*256*2);
  unsigned short* xbf1 = (unsigned short*)alloc((size_t)N*64*2);
  unsigned short* xbf2 = (unsigned short*)alloc((size_t)N*64*2);
  (void)ws_size; (void)n_in; (void)out_size;

  int gE = (E + 255)/256;
  int nelem = N + 1;
  int nb = (nelem + 255)/256;
  int gATT = (N + 63)/64;
  int gOUT = (N + 63)/64;
  int gSB  = (E + 4095)/4096;
  int nbin = (N + (1<<NBSH) - 1) >> NBSH;
  int gAGG = (N + 3)/4;
  float* outp = (float*)d_out;

  // weights for both layers + gmax/deg zeroing + rec2 slack init, one launch
  k_prep<<<2, 512, 0, stream>>>(W1, as1, ad1, b1, lb1, lW1,
                                W2, as2, ad2, b2, lb2, lW2,
                                wbigT, wattBsw, bcomb, gmax, rec2, deg, E, N);

  // CSR offsets (built once, reused by both layers); scan_add also seeds bincur
  k_hist<<<gE, 256, 0, stream>>>(dste, deg, E);
  k_scan_local<<<nb, 256, 0, stream>>>(deg, offs, blksum, nelem, N);
  k_scan_blk<<<1, 256, 0, stream>>>(blksum, nb);
  k_scan_add<<<nb, 256, 0, stream>>>(offs, blksum, bincur, nelem, N);

  // ----- layer 1 -----
  k_att <<<gATT, 256, 0, stream>>>(x, nullptr, wattBsw, pasrc, padst, xbf1, gmax, N);
  k_scatbin<<<gSB, 256, 0, stream>>>(srce, dste, pasrc, padst, bincur, gmax, rec1, E);
  k_place<<<nbin, 256, 0, stream>>>(rec1, offs, rec2, N);
  k_agg <<<gAGG, 256, 0, stream>>>(rec2, offs, xbf1, Abf, N);
  k_out <<<gOUT, 256, 0, stream>>>(Abf, xbf1, wbigT, bcomb, nullptr, xbf2, N);   // h = relu -> bf16

  // ----- layer 2 -----
  k_att <<<gATT, 256, 0, stream>>>(nullptr, xbf2, wattBsw + 1024, pasrc, padst, nullptr, gmax + 4, N);
  k_edge2<<<gE, 256, 0, stream>>>(rec2, pasrc, padst, gmax + 4, E);
  k_agg <<<gAGG, 256, 0, stream>>>(rec2, offs, xbf2, Abf, N);
  k_out <<<gOUT, 256, 0, stream>>>(Abf, xbf2, wbigT + 64*328, bcomb + 64, outp, nullptr, N);
}